// Round 9
// baseline (236.629 us; speedup 1.0000x reference)
//
#include <hip/hip_runtime.h>
#include <hip/hip_bf16.h>
#include <hip/hip_fp16.h>

// RecursiveNN forest bottom-up pass, fp32 in / fp32 out.
// forest_kernel: one block per EIGHTH-tree, BLOCK = 128 THREADS (2 waves).
// Evidence r4-r8: latency-bound (<13% all pipes); LDS-small + in-place (r7,
// 37.4 KB) beats LDS-big restructures (r8, 54.7 KB -> 2 blocks/CU). This
// round keeps r7's exact in-place schedule but halves the block: each wave
// holds 4 W col-groups (wh[4][8], 128 VGPR) so a 2-wave block covers all
// 128 features. Per-CU independent barrier chains: 2 -> 4 (4 blocks/CU at
// 37.4 KB LDS, 2 waves/SIMD at ~200 VGPR); rendezvous width 4 -> 2 waves;
// per-wave MFMA ILP doubles (8 independent split-K chains/step).
// prep converts W/P to f16 once. rnn_top: top 3 levels fp32 (verified).

typedef _Float16 f16_t;
typedef _Float16 f16x4 __attribute__((ext_vector_type(4)));
typedef _Float16 f16x8 __attribute__((ext_vector_type(8)));
typedef float f32x4 __attribute__((ext_vector_type(4)));

#define HSTRIDE 136   // f16 elems per row slot: 272 B, 16B-aligned

static __device__ __forceinline__ f32x4 mfma16(f16x8 a, f16x8 b, f32x4 c) {
    return __builtin_amdgcn_mfma_f32_16x16x32_f16(a, b, c, 0, 0, 0);
}

// One-shot: W [128,256] fp32 -> fp16 Wh; P [5,128] fp32 -> fp16 Ph.
__global__ void prep_kernel(const float* __restrict__ W, const float* __restrict__ P,
                            f16_t* __restrict__ Wh, f16_t* __restrict__ Ph) {
    if (blockIdx.x < 128) {
        const int i = blockIdx.x * 256 + threadIdx.x;
        Wh[i] = (f16_t)W[i];
    } else {
        for (int i = threadIdx.x; i < 640; i += 256) Ph[i] = (f16_t)P[i];
    }
}

// ---------------- fused levels 1..7 for one 64-pair-row eighth-tree ----------------
__global__ __launch_bounds__(128, 2)
void forest_kernel(const float* __restrict__ leaves,
                   const f16_t* __restrict__ Wh,
                   const f16_t* __restrict__ Ph,
                   const float* __restrict__ bW,
                   const float* __restrict__ bP,
                   f16_t* __restrict__ Q,          // [2048,128] eighth-roots
                   float* __restrict__ out)
{
    __shared__ f16_t AR[128 * HSTRIDE];          // 34816 B: leaf arena + ping-pong H
    __shared__ float OutB[640];                  // 2560 B: proj outbox, 127 rows x 5

    const int tid   = threadIdx.x;
    const int wave  = tid >> 6;                  // 0 or 1
    const int lane  = tid & 63;
    const int mlane = lane & 15;
    const int q     = lane >> 4;
    const int tree  = blockIdx.x >> 3;
    const int e     = blockIdx.x & 7;
    const float* leafbase = leaves + (size_t)blockIdx.x * 16384;

    // W b-frags: wave w holds cols [64w, 64w+64) as 4 col-groups of 16
    f16x8 wh[4][8];
    float bwv[4];
    #pragma unroll
    for (int n = 0; n < 4; ++n) {
        const int col = wave * 64 + n * 16 + mlane;
        bwv[n] = bW[col];
        #pragma unroll
        for (int k = 0; k < 8; ++k)
            wh[n][k] = *(const f16x8*)&Wh[col * 256 + k * 32 + q * 8];
    }

    // P b-frags, N padded 5->16 (zero rows for mlane>=5)
    f16x8 pb[4] = {};
    if (mlane < 5) {
        #pragma unroll
        for (int kb = 0; kb < 4; ++kb)
            pb[kb] = *(const f16x8*)&Ph[mlane * 128 + kb * 32 + q * 8];
    }
    const float bpv = (mlane < 5) ? bP[mlane] : 0.f;

    // ---- whole-block leaf preload: 64 KB fp32 -> f16 arena, 4 batches x 8 ----
    #pragma unroll
    for (int b = 0; b < 4; ++b) {
        float4 t[8];
        #pragma unroll
        for (int r = 0; r < 8; ++r)
            t[r] = ((const float4*)leafbase)[tid + (b * 8 + r) * 128];
        #pragma unroll
        for (int r = 0; r < 8; ++r) {
            const int idx = tid + (b * 8 + r) * 128;   // 4096 float4 = 128 leaf rows
            const int row = idx >> 5;
            const int c4  = idx & 31;
            f16x4 t4 = { (f16_t)t[r].x, (f16_t)t[r].y, (f16_t)t[r].z, (f16_t)t[r].w };
            *(f16x4*)&AR[row * HSTRIDE + c4 * 4] = t4;
        }
    }

    // read A-frags for a 32-row window at src (verified fragment pattern)
    auto read_frags = [&](const f16_t* src, f16x8* af) {
        #pragma unroll
        for (int k = 0; k < 8; ++k) {
            const int off  = k * 64 + q * 16;    // byte offset in 512B pair-row
            const int trow = off >> 8;
            const int ce   = (off & 255) >> 1;
            af[k] = *(const f16x8*)&src[(2 * mlane + trow) * HSTRIDE + ce];
        }
    };
    // MFMA: 4 col-groups x split-K(2x4) = 8 independent chains; bias+relu -> frame
    auto mfma_write = [&](const f16x8* af, f16_t* dst) {
        f32x4 a[4] = {{}, {}, {}, {}}, b[4] = {{}, {}, {}, {}};
        #pragma unroll
        for (int k = 0; k < 4; ++k) {
            #pragma unroll
            for (int n = 0; n < 4; ++n) a[n] = mfma16(af[k], wh[n][k], a[n]);
        }
        #pragma unroll
        for (int k = 4; k < 8; ++k) {
            #pragma unroll
            for (int n = 0; n < 4; ++n) b[n] = mfma16(af[k], wh[n][k], b[n]);
        }
        #pragma unroll
        for (int n = 0; n < 4; ++n) {
            #pragma unroll
            for (int r = 0; r < 4; ++r) {
                float v = fmaxf(a[n][r] + b[n][r] + bwv[n], 0.f);
                dst[(q * 4 + r) * HSTRIDE + wave * 64 + n * 16 + mlane] = (f16_t)v;
            }
        }
    };
    // proj of 16 H rows at hb -> OutB rows [orow0, orow0+valid); 2x2 chains
    auto proj_to_outb = [&](const f16_t* hb, int orow0, int valid) {
        f32x4 p0 = {}, p1 = {};
        {
            const f16x8 h0 = *(const f16x8*)&hb[mlane * HSTRIDE + 0 * 32 + q * 8];
            const f16x8 h1 = *(const f16x8*)&hb[mlane * HSTRIDE + 1 * 32 + q * 8];
            const f16x8 h2 = *(const f16x8*)&hb[mlane * HSTRIDE + 2 * 32 + q * 8];
            const f16x8 h3 = *(const f16x8*)&hb[mlane * HSTRIDE + 3 * 32 + q * 8];
            p0 = mfma16(h0, pb[0], p0); p1 = mfma16(h1, pb[1], p1);
            p0 = mfma16(h2, pb[2], p0); p1 = mfma16(h3, pb[3], p1);
        }
        if (mlane < 5) {
            #pragma unroll
            for (int r = 0; r < 4; ++r) {
                const int row = q * 4 + r;       // D layout: row=q*4+r, col=mlane (verified)
                if (row < valid) OutB[(orow0 + row) * 5 + mlane] = p0[r] + p1[r] + bpv;
            }
        }
    };

    __syncthreads();                                           // B1: arena visible

    // ---- level 1: 4 in-arena ping-pong steps ----
    // step c: read rows [32c,32c+32) ; barrier ; write [16c,16c+16)
    #pragma unroll
    for (int c = 0; c < 4; ++c) {
        f16x8 af[8];
        read_frags(&AR[(32 * c) * HSTRIDE], af);
        __syncthreads();                                       // B2..B5
        mfma_write(af, &AR[(16 * c) * HSTRIDE]);
    }
    __syncthreads();                                           // B6: L1 rows 0-63 final

    // ---- Seg A: L1 proj (wave w: chunks 2w,2w+1) + L2 (reads 0-63 -> 64-95) ----
    proj_to_outb(&AR[(32 * wave) * HSTRIDE],      32 * wave,      16);
    proj_to_outb(&AR[(32 * wave + 16) * HSTRIDE], 32 * wave + 16, 16);
    {
        f16x8 af[8];
        read_frags(&AR[0], af);
        mfma_write(af, &AR[64 * HSTRIDE]);
        read_frags(&AR[32 * HSTRIDE], af);
        mfma_write(af, &AR[80 * HSTRIDE]);
    }
    __syncthreads();                                           // B7

    // ---- Seg B: L2 proj (w0,w1) + L3 (reads 64-95 -> 0-15) ----
    if (wave == 0) proj_to_outb(&AR[64 * HSTRIDE], 64, 16);
    if (wave == 1) proj_to_outb(&AR[80 * HSTRIDE], 80, 16);
    { f16x8 af[8]; read_frags(&AR[64 * HSTRIDE], af); mfma_write(af, &AR[0]); }
    __syncthreads();                                           // B8

    // ---- Seg C: L3 proj (w0) + L4 (reads 0-31 -> 32-47, valid 8) ----
    if (wave == 0) proj_to_outb(&AR[0], 96, 16);
    { f16x8 af[8]; read_frags(&AR[0], af); mfma_write(af, &AR[32 * HSTRIDE]); }
    __syncthreads();                                           // B9

    // ---- Seg D: L4 proj (w1) + L5 (reads 32-63 -> 0-15, valid 4) ----
    if (wave == 1) proj_to_outb(&AR[32 * HSTRIDE], 112, 8);
    { f16x8 af[8]; read_frags(&AR[32 * HSTRIDE], af); mfma_write(af, &AR[0]); }
    __syncthreads();                                           // B10

    // ---- Seg E: L5 proj (w0) + L6 (reads 0-31 -> 32-47, valid 2) ----
    if (wave == 0) proj_to_outb(&AR[0], 120, 4);
    { f16x8 af[8]; read_frags(&AR[0], af); mfma_write(af, &AR[32 * HSTRIDE]); }
    __syncthreads();                                           // B11

    // ---- Seg F: L6 proj (w1) + L7 (reads 32-63 -> 0-15, valid 1) ----
    if (wave == 1) proj_to_outb(&AR[32 * HSTRIDE], 124, 2);
    { f16x8 af[8]; read_frags(&AR[32 * HSTRIDE], af); mfma_write(af, &AR[0]); }
    __syncthreads();                                           // B12

    // ---- Seg G: L7 proj (w0) + Q store (AR row 0 = eighth-root) ----
    if (wave == 0) proj_to_outb(&AR[0], 126, 1);
    if (tid < 16)
        *(uint4*)&Q[(size_t)blockIdx.x * 128 + tid * 8] = *(const uint4*)&AR[tid * 8];
    __syncthreads();                                           // B13: outbox complete

    // ---- flush outbox: 127 rows x 5 floats, one global-store pass ----
    for (int t2 = tid; t2 < 635; t2 += 128) {
        const int lrow = t2 / 5;
        const int cls  = t2 - lrow * 5;
        int j, i;
        if      (lrow <  64) { j = 1; i = lrow;       }
        else if (lrow <  96) { j = 2; i = lrow - 64;  }
        else if (lrow < 112) { j = 3; i = lrow - 96;  }
        else if (lrow < 120) { j = 4; i = lrow - 112; }
        else if (lrow < 124) { j = 5; i = lrow - 120; }
        else if (lrow < 126) { j = 6; i = lrow - 124; }
        else                 { j = 7; i = 0;          }
        const size_t grow = (size_t)256 * (1024 - (2048 >> j))
                          + (size_t)tree * (1024 >> j) + (size_t)e * (128 >> j) + i;
        out[grow * 5 + cls] = OutB[t2];
    }
}

// ---------------- top 3 levels (8 eighth-roots -> 4 -> 2 -> 1), fp32 ----------------
__global__ __launch_bounds__(128, 4)
void rnn_top_kernel(const f16_t* __restrict__ Q,
                    const float* __restrict__ W,
                    const float* __restrict__ bW,
                    const float* __restrict__ P,
                    const float* __restrict__ bP,
                    float* __restrict__ out)
{
    __shared__ float qs[1024];
    __shared__ float hs[896];    // [0,512): level-8 nodes, [512,768): level-9, [768,896): root
    const int t    = threadIdx.x;
    const int tree = blockIdx.x;

    #pragma unroll
    for (int i = 0; i < 8; ++i)
        qs[t + i * 128] = (float)Q[(size_t)tree * 1024 + t + i * 128];
    __syncthreads();

    const float* wr = W + t * 256;

    // level 8: 4 nodes from 8 eighth-roots
    float s8[4];
    #pragma unroll
    for (int n = 0; n < 4; ++n) s8[n] = bW[t];
    for (int k = 0; k < 256; k += 4) {
        const float4 wv = *(const float4*)(wr + k);
        #pragma unroll
        for (int n = 0; n < 4; ++n) {
            const float* qb = qs + n * 256 + k;
            s8[n] += wv.x * qb[0] + wv.y * qb[1] + wv.z * qb[2] + wv.w * qb[3];
        }
    }
    #pragma unroll
    for (int n = 0; n < 4; ++n) hs[n * 128 + t] = fmaxf(s8[n], 0.f);
    __syncthreads();

    // level 9: 2 nodes
    float s9[2];
    s9[0] = s9[1] = bW[t];
    for (int k = 0; k < 256; k += 4) {
        const float4 wv = *(const float4*)(wr + k);
        #pragma unroll
        for (int m = 0; m < 2; ++m) {
            const float* hb = hs + m * 256 + k;
            s9[m] += wv.x * hb[0] + wv.y * hb[1] + wv.z * hb[2] + wv.w * hb[3];
        }
    }
    hs[512 + t] = fmaxf(s9[0], 0.f);
    hs[640 + t] = fmaxf(s9[1], 0.f);
    __syncthreads();

    // level 10: root
    float s10 = bW[t];
    for (int k = 0; k < 256; k += 4) {
        const float4 wv = *(const float4*)(wr + k);
        const float* hb = hs + 512 + k;
        s10 += wv.x * hb[0] + wv.y * hb[1] + wv.z * hb[2] + wv.w * hb[3];
    }
    hs[768 + t] = fmaxf(s10, 0.f);
    __syncthreads();

    // projections: 7 nodes x 5 classes
    if (t < 35) {
        const int node = t / 5, c = t % 5;
        float s = bP[c];
        const float* hb = hs + node * 128;
        for (int k = 0; k < 128; ++k) s += hb[k] * P[c * 128 + k];
        size_t row;
        if (node < 4)      row = 260096 + (size_t)tree * 4 + node;        // level 8 (n=4/tree)
        else if (node < 6) row = 261120 + (size_t)tree * 2 + (node - 4);  // level 9 (n=2/tree)
        else               row = 261632 + (size_t)tree;                   // level 10 root
        out[row * 5 + c] = s;
    }
}

extern "C" void kernel_launch(void* const* d_in, const int* in_sizes, int n_in,
                              void* d_out, int out_size, void* d_ws, size_t ws_size,
                              hipStream_t stream) {
    const float* leaves = (const float*)d_in[0];   // [256,1024,128] fp32
    const float* W      = (const float*)d_in[1];   // [128,256] fp32
    const float* bW     = (const float*)d_in[2];   // [128] fp32
    const float* P      = (const float*)d_in[3];   // [5,128] fp32
    const float* bP     = (const float*)d_in[4];   // [5] fp32
    float* out = (float*)d_out;                    // [256*1023, 5] fp32

    // ws layout (f16 elems): Wh 32768 | Ph 1024 | Q 262144  (~592 KB)
    f16_t* Wh = (f16_t*)d_ws;
    f16_t* Ph = Wh + 32768;
    f16_t* Q  = Wh + 32768 + 1024;

    prep_kernel<<<dim3(129), dim3(256), 0, stream>>>(W, P, Wh, Ph);
    forest_kernel<<<dim3(2048), dim3(128), 0, stream>>>(leaves, Wh, Ph, bW, bP, Q, out);
    rnn_top_kernel<<<dim3(256), dim3(128), 0, stream>>>(Q, W, bW, P, bP, out);
}

// Round 10
// 228.515 us; speedup vs baseline: 1.0355x; 1.0355x over previous
//
#include <hip/hip_runtime.h>
#include <hip/hip_bf16.h>
#include <hip/hip_fp16.h>

// RecursiveNN forest bottom-up pass, fp32 in / fp32 out.
// forest_kernel: one block per FOUR eighth-trees (G=4), processed
// sequentially in the same 34.8 KB LDS arena (r7's exact in-place ping-pong
// schedule and wave assignments, the best-measured structure: 220.5 us).
// Round-10 additions (evidence r3-r9: latency-bound, per-block serial chain
// is the wall; wins came from removing work from the barrier path):
//  (1) G=4 trees/block: wh/pb setup amortized 4x; grid 2048 -> 512 =
//      exactly 2 blocks/CU, zero dispatch ramp/tail.
//  (2) T14 register prefetch: tree g+1's 16 float4 leaf loads issued inside
//      Seg A (covered by ~1200 cyc of proj+L2 MFMA before the next barrier's
//      vmcnt drain) -> per-tree serial preload off the critical path.
//      Plain __syncthreads everywhere (no raw-barrier risk).
//  (3) VGPR ~214 (r7 ~150 + t[16]); tripwire for spill: WRITE_SIZE > 5.8 MB.
// prep converts W/P to f16 once. rnn_top: top 3 levels fp32 (verified).

typedef _Float16 f16_t;
typedef _Float16 f16x4 __attribute__((ext_vector_type(4)));
typedef _Float16 f16x8 __attribute__((ext_vector_type(8)));
typedef float f32x4 __attribute__((ext_vector_type(4)));

#define HSTRIDE 136   // f16 elems per row slot: 272 B, 16B-aligned

static __device__ __forceinline__ f32x4 mfma16(f16x8 a, f16x8 b, f32x4 c) {
    return __builtin_amdgcn_mfma_f32_16x16x32_f16(a, b, c, 0, 0, 0);
}

// One-shot: W [128,256] fp32 -> fp16 Wh; P [5,128] fp32 -> fp16 Ph.
__global__ void prep_kernel(const float* __restrict__ W, const float* __restrict__ P,
                            f16_t* __restrict__ Wh, f16_t* __restrict__ Ph) {
    if (blockIdx.x < 128) {
        const int i = blockIdx.x * 256 + threadIdx.x;
        Wh[i] = (f16_t)W[i];
    } else {
        for (int i = threadIdx.x; i < 640; i += 256) Ph[i] = (f16_t)P[i];
    }
}

// ---------------- fused levels 1..7 for FOUR 64-pair-row eighth-trees ----------------
__global__ __launch_bounds__(256, 2)
void forest_kernel(const float* __restrict__ leaves,
                   const f16_t* __restrict__ Wh,
                   const f16_t* __restrict__ Ph,
                   const float* __restrict__ bW,
                   const float* __restrict__ bP,
                   f16_t* __restrict__ Q,          // [2048,128] eighth-roots
                   float* __restrict__ out)
{
    __shared__ f16_t AR[128 * HSTRIDE];          // 34816 B: leaf arena + ping-pong H
    __shared__ float OutB[640];                  // 2560 B: proj outbox, 127 rows x 5

    const int tid   = threadIdx.x;
    const int wave  = tid >> 6;
    const int lane  = tid & 63;
    const int mlane = lane & 15;
    const int q     = lane >> 4;
    const int E0    = blockIdx.x * 4;            // first eighth-tree index

    // issue tree-0 leaf loads first; wh/pb setup overlaps their latency
    float4 t[16];
    {
        const float* lb0 = leaves + (size_t)E0 * 16384;
        #pragma unroll
        for (int r = 0; r < 16; ++r)
            t[r] = ((const float4*)lb0)[tid + r * 256];
    }

    // W b-frags (gemm_bt, verified): lane holds W[col][k*32 + q*8 + e]
    f16x8 wh[2][8];
    float bwv[2];
    #pragma unroll
    for (int n = 0; n < 2; ++n) {
        const int col = wave * 32 + n * 16 + mlane;
        bwv[n] = bW[col];
        #pragma unroll
        for (int k = 0; k < 8; ++k)
            wh[n][k] = *(const f16x8*)&Wh[col * 256 + k * 32 + q * 8];
    }

    // P b-frags, N padded 5->16 (zero rows for mlane>=5)
    f16x8 pb[4] = {};
    if (mlane < 5) {
        #pragma unroll
        for (int kb = 0; kb < 4; ++kb)
            pb[kb] = *(const f16x8*)&Ph[mlane * 128 + kb * 32 + q * 8];
    }
    const float bpv = (mlane < 5) ? bP[mlane] : 0.f;

    // read A-frags for a 32-row window at src (verified fragment pattern)
    auto read_frags = [&](const f16_t* src, f16x8* af) {
        #pragma unroll
        for (int k = 0; k < 8; ++k) {
            const int off  = k * 64 + q * 16;    // byte offset in 512B pair-row
            const int trow = off >> 8;
            const int ce   = (off & 255) >> 1;
            af[k] = *(const f16x8*)&src[(2 * mlane + trow) * HSTRIDE + ce];
        }
    };
    // MFMA (split-K: 4 independent chains of 4) + bias + relu -> 16-row frame
    auto mfma_write = [&](const f16x8* af, f16_t* dst) {
        f32x4 a0 = {}, b0 = {}, a1 = {}, b1 = {};
        #pragma unroll
        for (int k = 0; k < 4; ++k) {
            a0 = mfma16(af[k], wh[0][k], a0);
            a1 = mfma16(af[k], wh[1][k], a1);
        }
        #pragma unroll
        for (int k = 4; k < 8; ++k) {
            b0 = mfma16(af[k], wh[0][k], b0);
            b1 = mfma16(af[k], wh[1][k], b1);
        }
        #pragma unroll
        for (int r = 0; r < 4; ++r) {
            float v0 = fmaxf(a0[r] + b0[r] + bwv[0], 0.f);
            float v1 = fmaxf(a1[r] + b1[r] + bwv[1], 0.f);
            dst[(q * 4 + r) * HSTRIDE + wave * 32 + mlane]      = (f16_t)v0;
            dst[(q * 4 + r) * HSTRIDE + wave * 32 + 16 + mlane] = (f16_t)v1;
        }
    };
    // proj of 16 H rows at hb -> OutB rows [orow0, orow0+valid); 2x2 chains
    auto proj_to_outb = [&](const f16_t* hb, int orow0, int valid) {
        f32x4 p0 = {}, p1 = {};
        {
            const f16x8 h0 = *(const f16x8*)&hb[mlane * HSTRIDE + 0 * 32 + q * 8];
            const f16x8 h1 = *(const f16x8*)&hb[mlane * HSTRIDE + 1 * 32 + q * 8];
            const f16x8 h2 = *(const f16x8*)&hb[mlane * HSTRIDE + 2 * 32 + q * 8];
            const f16x8 h3 = *(const f16x8*)&hb[mlane * HSTRIDE + 3 * 32 + q * 8];
            p0 = mfma16(h0, pb[0], p0); p1 = mfma16(h1, pb[1], p1);
            p0 = mfma16(h2, pb[2], p0); p1 = mfma16(h3, pb[3], p1);
        }
        if (mlane < 5) {
            #pragma unroll
            for (int r = 0; r < 4; ++r) {
                const int row = q * 4 + r;       // D layout: row=q*4+r, col=mlane (verified)
                if (row < valid) OutB[(orow0 + row) * 5 + mlane] = p0[r] + p1[r] + bpv;
            }
        }
    };

    #pragma unroll 1
    for (int g = 0; g < 4; ++g) {
        const int E    = E0 + g;
        const int tree = E >> 3;
        const int e    = E & 7;

        // ---- store prefetched leaves (t[]) -> f16 arena ----
        #pragma unroll
        for (int r = 0; r < 16; ++r) {
            const int idx = tid + r * 256;             // 4096 float4 = 128 leaf rows
            const int row = idx >> 5;
            const int c4  = idx & 31;
            f16x4 t4 = { (f16_t)t[r].x, (f16_t)t[r].y, (f16_t)t[r].z, (f16_t)t[r].w };
            *(f16x4*)&AR[row * HSTRIDE + c4 * 4] = t4;
        }
        __syncthreads();                                       // B1: arena visible

        // ---- level 1: 4 in-arena ping-pong steps ----
        // step c: read rows [32c,32c+32) ; barrier ; write [16c,16c+16)
        #pragma unroll
        for (int c = 0; c < 4; ++c) {
            f16x8 af[8];
            read_frags(&AR[(32 * c) * HSTRIDE], af);
            __syncthreads();                                   // B2..B5
            mfma_write(af, &AR[(16 * c) * HSTRIDE]);
        }
        __syncthreads();                                       // B6: L1 rows 0-63 final

        // ---- Seg A: prefetch next tree + L1 proj (all waves) + L2 (0-63 -> 64-95) ----
        if (g < 3) {                                           // issue early; Seg A's MFMA
            const float* lbn = leaves + (size_t)(E + 1) * 16384;   // work covers latency
            #pragma unroll
            for (int r = 0; r < 16; ++r)
                t[r] = ((const float4*)lbn)[tid + r * 256];
        }
        proj_to_outb(&AR[(16 * wave) * HSTRIDE], 16 * wave, 16);
        {
            f16x8 af[8];
            read_frags(&AR[0], af);
            mfma_write(af, &AR[64 * HSTRIDE]);
            read_frags(&AR[32 * HSTRIDE], af);
            mfma_write(af, &AR[80 * HSTRIDE]);
        }
        __syncthreads();                                       // B7 (drains prefetch)

        // ---- Seg B: L2 proj + L3 (reads 64-95, writes 0-15) ----
        if (wave == 0) proj_to_outb(&AR[64 * HSTRIDE], 64, 16);
        if (wave == 1) proj_to_outb(&AR[80 * HSTRIDE], 80, 16);
        { f16x8 af[8]; read_frags(&AR[64 * HSTRIDE], af); mfma_write(af, &AR[0]); }
        __syncthreads();                                       // B8

        // ---- Seg C: L3 proj + L4 (reads 0-31, writes 32-47, valid 8) ----
        if (wave == 2) proj_to_outb(&AR[0], 96, 16);
        { f16x8 af[8]; read_frags(&AR[0], af); mfma_write(af, &AR[32 * HSTRIDE]); }
        __syncthreads();                                       // B9

        // ---- Seg D: L4 proj + L5 (reads 32-63, writes 0-15, valid 4) ----
        if (wave == 3) proj_to_outb(&AR[32 * HSTRIDE], 112, 8);
        { f16x8 af[8]; read_frags(&AR[32 * HSTRIDE], af); mfma_write(af, &AR[0]); }
        __syncthreads();                                       // B10

        // ---- Seg E: L5 proj + L6 (reads 0-31, writes 32-47, valid 2) ----
        if (wave == 0) proj_to_outb(&AR[0], 120, 4);
        { f16x8 af[8]; read_frags(&AR[0], af); mfma_write(af, &AR[32 * HSTRIDE]); }
        __syncthreads();                                       // B11

        // ---- Seg F: L6 proj + L7 (reads 32-63, writes 0-15, valid 1) ----
        if (wave == 1) proj_to_outb(&AR[32 * HSTRIDE], 124, 2);
        { f16x8 af[8]; read_frags(&AR[32 * HSTRIDE], af); mfma_write(af, &AR[0]); }
        __syncthreads();                                       // B12

        // ---- Seg G: L7 proj + Q store (AR row 0 = eighth-root) ----
        if (wave == 2) proj_to_outb(&AR[0], 126, 1);
        if (tid < 16)
            *(uint4*)&Q[(size_t)E * 128 + tid * 8] = *(const uint4*)&AR[tid * 8];
        __syncthreads();                                       // B13: outbox complete,
                                                               // all AR reads done

        // ---- flush outbox: 127 rows x 5 floats (fire-and-forget stores) ----
        for (int t2 = tid; t2 < 635; t2 += 256) {
            const int lrow = t2 / 5;
            const int cls  = t2 - lrow * 5;
            int j, i;
            if      (lrow <  64) { j = 1; i = lrow;       }
            else if (lrow <  96) { j = 2; i = lrow - 64;  }
            else if (lrow < 112) { j = 3; i = lrow - 96;  }
            else if (lrow < 120) { j = 4; i = lrow - 112; }
            else if (lrow < 124) { j = 5; i = lrow - 120; }
            else if (lrow < 126) { j = 6; i = lrow - 124; }
            else                 { j = 7; i = 0;          }
            const size_t grow = (size_t)256 * (1024 - (2048 >> j))
                              + (size_t)tree * (1024 >> j) + (size_t)e * (128 >> j) + i;
            out[grow * 5 + cls] = OutB[t2];
        }
        // next iteration's AR store is safe: all AR reads done at B13; OutB
        // is only rewritten after tree g+1's B6 (flush LDS-reads long done).
    }
}

// ---------------- top 3 levels (8 eighth-roots -> 4 -> 2 -> 1), fp32 ----------------
__global__ __launch_bounds__(128, 4)
void rnn_top_kernel(const f16_t* __restrict__ Q,
                    const float* __restrict__ W,
                    const float* __restrict__ bW,
                    const float* __restrict__ P,
                    const float* __restrict__ bP,
                    float* __restrict__ out)
{
    __shared__ float qs[1024];
    __shared__ float hs[896];    // [0,512): level-8 nodes, [512,768): level-9, [768,896): root
    const int t    = threadIdx.x;
    const int tree = blockIdx.x;

    #pragma unroll
    for (int i = 0; i < 8; ++i)
        qs[t + i * 128] = (float)Q[(size_t)tree * 1024 + t + i * 128];
    __syncthreads();

    const float* wr = W + t * 256;

    // level 8: 4 nodes from 8 eighth-roots
    float s8[4];
    #pragma unroll
    for (int n = 0; n < 4; ++n) s8[n] = bW[t];
    for (int k = 0; k < 256; k += 4) {
        const float4 wv = *(const float4*)(wr + k);
        #pragma unroll
        for (int n = 0; n < 4; ++n) {
            const float* qb = qs + n * 256 + k;
            s8[n] += wv.x * qb[0] + wv.y * qb[1] + wv.z * qb[2] + wv.w * qb[3];
        }
    }
    #pragma unroll
    for (int n = 0; n < 4; ++n) hs[n * 128 + t] = fmaxf(s8[n], 0.f);
    __syncthreads();

    // level 9: 2 nodes
    float s9[2];
    s9[0] = s9[1] = bW[t];
    for (int k = 0; k < 256; k += 4) {
        const float4 wv = *(const float4*)(wr + k);
        #pragma unroll
        for (int m = 0; m < 2; ++m) {
            const float* hb = hs + m * 256 + k;
            s9[m] += wv.x * hb[0] + wv.y * hb[1] + wv.z * hb[2] + wv.w * hb[3];
        }
    }
    hs[512 + t] = fmaxf(s9[0], 0.f);
    hs[640 + t] = fmaxf(s9[1], 0.f);
    __syncthreads();

    // level 10: root
    float s10 = bW[t];
    for (int k = 0; k < 256; k += 4) {
        const float4 wv = *(const float4*)(wr + k);
        const float* hb = hs + 512 + k;
        s10 += wv.x * hb[0] + wv.y * hb[1] + wv.z * hb[2] + wv.w * hb[3];
    }
    hs[768 + t] = fmaxf(s10, 0.f);
    __syncthreads();

    // projections: 7 nodes x 5 classes
    if (t < 35) {
        const int node = t / 5, c = t % 5;
        float s = bP[c];
        const float* hb = hs + node * 128;
        for (int k = 0; k < 128; ++k) s += hb[k] * P[c * 128 + k];
        size_t row;
        if (node < 4)      row = 260096 + (size_t)tree * 4 + node;        // level 8 (n=4/tree)
        else if (node < 6) row = 261120 + (size_t)tree * 2 + (node - 4);  // level 9 (n=2/tree)
        else               row = 261632 + (size_t)tree;                   // level 10 root
        out[row * 5 + c] = s;
    }
}

extern "C" void kernel_launch(void* const* d_in, const int* in_sizes, int n_in,
                              void* d_out, int out_size, void* d_ws, size_t ws_size,
                              hipStream_t stream) {
    const float* leaves = (const float*)d_in[0];   // [256,1024,128] fp32
    const float* W      = (const float*)d_in[1];   // [128,256] fp32
    const float* bW     = (const float*)d_in[2];   // [128] fp32
    const float* P      = (const float*)d_in[3];   // [5,128] fp32
    const float* bP     = (const float*)d_in[4];   // [5] fp32
    float* out = (float*)d_out;                    // [256*1023, 5] fp32

    // ws layout (f16 elems): Wh 32768 | Ph 1024 | Q 262144  (~592 KB)
    f16_t* Wh = (f16_t*)d_ws;
    f16_t* Ph = Wh + 32768;
    f16_t* Q  = Wh + 32768 + 1024;

    prep_kernel<<<dim3(129), dim3(256), 0, stream>>>(W, P, Wh, Ph);
    forest_kernel<<<dim3(512), dim3(256), 0, stream>>>(leaves, Wh, Ph, bW, bP, Q, out);
    rnn_top_kernel<<<dim3(256), dim3(128), 0, stream>>>(Q, W, bW, P, bP, out);
}

// Round 11
// 225.639 us; speedup vs baseline: 1.0487x; 1.0127x over previous
//
#include <hip/hip_runtime.h>
#include <hip/hip_bf16.h>
#include <hip/hip_fp16.h>

// RecursiveNN forest bottom-up pass, fp32 in / fp32 out.
// forest_kernel: one block per EIGHTH-tree (64 level-1 pair-rows) — exact
// r7 structure (best measured: 220.5 us), which won over all structural
// variants (bigger segments r8, 2-wave blocks r9, G=4 batching r10).
// Single change vs r7: L1 uses ONE barrier instead of 4 via 2-phase
// ordering — read ALL frags of rows 0-63 (af0/af1), barrier, write 0-31,
// read rows 64-127 (never written in L1), write 32-63. Every write window's
// readers drained at the single barrier; post-barrier reads touch only
// untouched rows. 10 barriers total (was 13). +32 VGPR (af live across
// barrier), ~160 total — no spill at (256,2); tripwire WRITE_SIZE>5.8MB.
// prep converts W/P to f16 once. rnn_top: top 3 levels fp32 (verified).

typedef _Float16 f16_t;
typedef _Float16 f16x4 __attribute__((ext_vector_type(4)));
typedef _Float16 f16x8 __attribute__((ext_vector_type(8)));
typedef float f32x4 __attribute__((ext_vector_type(4)));

#define HSTRIDE 136   // f16 elems per row slot: 272 B, 16B-aligned

static __device__ __forceinline__ f32x4 mfma16(f16x8 a, f16x8 b, f32x4 c) {
    return __builtin_amdgcn_mfma_f32_16x16x32_f16(a, b, c, 0, 0, 0);
}

// One-shot: W [128,256] fp32 -> fp16 Wh; P [5,128] fp32 -> fp16 Ph.
__global__ void prep_kernel(const float* __restrict__ W, const float* __restrict__ P,
                            f16_t* __restrict__ Wh, f16_t* __restrict__ Ph) {
    if (blockIdx.x < 128) {
        const int i = blockIdx.x * 256 + threadIdx.x;
        Wh[i] = (f16_t)W[i];
    } else {
        for (int i = threadIdx.x; i < 640; i += 256) Ph[i] = (f16_t)P[i];
    }
}

// ---------------- fused levels 1..7 for one 64-pair-row eighth-tree ----------------
__global__ __launch_bounds__(256, 2)
void forest_kernel(const float* __restrict__ leaves,
                   const f16_t* __restrict__ Wh,
                   const f16_t* __restrict__ Ph,
                   const float* __restrict__ bW,
                   const float* __restrict__ bP,
                   f16_t* __restrict__ Q,          // [2048,128] eighth-roots
                   float* __restrict__ out)
{
    __shared__ f16_t AR[128 * HSTRIDE];          // 34816 B: leaf arena + ping-pong H
    __shared__ float OutB[640];                  // 2560 B: proj outbox, 127 rows x 5

    const int tid   = threadIdx.x;
    const int wave  = tid >> 6;
    const int lane  = tid & 63;
    const int mlane = lane & 15;
    const int q     = lane >> 4;
    const int tree  = blockIdx.x >> 3;
    const int e     = blockIdx.x & 7;
    const float* leafbase = leaves + (size_t)blockIdx.x * 16384;

    // W b-frags (gemm_bt, verified): lane holds W[col][k*32 + q*8 + e]
    f16x8 wh[2][8];
    float bwv[2];
    #pragma unroll
    for (int n = 0; n < 2; ++n) {
        const int col = wave * 32 + n * 16 + mlane;
        bwv[n] = bW[col];
        #pragma unroll
        for (int k = 0; k < 8; ++k)
            wh[n][k] = *(const f16x8*)&Wh[col * 256 + k * 32 + q * 8];
    }

    // P b-frags, N padded 5->16 (zero rows for mlane>=5)
    f16x8 pb[4] = {};
    if (mlane < 5) {
        #pragma unroll
        for (int kb = 0; kb < 4; ++kb)
            pb[kb] = *(const f16x8*)&Ph[mlane * 128 + kb * 32 + q * 8];
    }
    const float bpv = (mlane < 5) ? bP[mlane] : 0.f;

    // ---- whole-block leaf preload: 64 KB fp32 -> f16 arena, 16 loads in flight ----
    {
        float4 t[16];
        #pragma unroll
        for (int r = 0; r < 16; ++r)
            t[r] = ((const float4*)leafbase)[tid + r * 256];
        #pragma unroll
        for (int r = 0; r < 16; ++r) {
            const int idx = tid + r * 256;             // 4096 float4 = 128 leaf rows
            const int row = idx >> 5;
            const int c4  = idx & 31;
            f16x4 t4 = { (f16_t)t[r].x, (f16_t)t[r].y, (f16_t)t[r].z, (f16_t)t[r].w };
            *(f16x4*)&AR[row * HSTRIDE + c4 * 4] = t4;
        }
    }

    // read A-frags for a 32-row window at src (verified fragment pattern)
    auto read_frags = [&](const f16_t* src, f16x8* af) {
        #pragma unroll
        for (int k = 0; k < 8; ++k) {
            const int off  = k * 64 + q * 16;    // byte offset in 512B pair-row
            const int trow = off >> 8;
            const int ce   = (off & 255) >> 1;
            af[k] = *(const f16x8*)&src[(2 * mlane + trow) * HSTRIDE + ce];
        }
    };
    // MFMA (split-K: 4 independent chains of 4) + bias + relu -> 16-row frame
    auto mfma_write = [&](const f16x8* af, f16_t* dst) {
        f32x4 a0 = {}, b0 = {}, a1 = {}, b1 = {};
        #pragma unroll
        for (int k = 0; k < 4; ++k) {
            a0 = mfma16(af[k], wh[0][k], a0);
            a1 = mfma16(af[k], wh[1][k], a1);
        }
        #pragma unroll
        for (int k = 4; k < 8; ++k) {
            b0 = mfma16(af[k], wh[0][k], b0);
            b1 = mfma16(af[k], wh[1][k], b1);
        }
        #pragma unroll
        for (int r = 0; r < 4; ++r) {
            float v0 = fmaxf(a0[r] + b0[r] + bwv[0], 0.f);
            float v1 = fmaxf(a1[r] + b1[r] + bwv[1], 0.f);
            dst[(q * 4 + r) * HSTRIDE + wave * 32 + mlane]      = (f16_t)v0;
            dst[(q * 4 + r) * HSTRIDE + wave * 32 + 16 + mlane] = (f16_t)v1;
        }
    };
    // proj of 16 H rows at hb -> OutB rows [orow0, orow0+valid); 2x2 chains
    auto proj_to_outb = [&](const f16_t* hb, int orow0, int valid) {
        f32x4 p0 = {}, p1 = {};
        {
            const f16x8 h0 = *(const f16x8*)&hb[mlane * HSTRIDE + 0 * 32 + q * 8];
            const f16x8 h1 = *(const f16x8*)&hb[mlane * HSTRIDE + 1 * 32 + q * 8];
            const f16x8 h2 = *(const f16x8*)&hb[mlane * HSTRIDE + 2 * 32 + q * 8];
            const f16x8 h3 = *(const f16x8*)&hb[mlane * HSTRIDE + 3 * 32 + q * 8];
            p0 = mfma16(h0, pb[0], p0); p1 = mfma16(h1, pb[1], p1);
            p0 = mfma16(h2, pb[2], p0); p1 = mfma16(h3, pb[3], p1);
        }
        if (mlane < 5) {
            #pragma unroll
            for (int r = 0; r < 4; ++r) {
                const int row = q * 4 + r;       // D layout: row=q*4+r, col=mlane (verified)
                if (row < valid) OutB[(orow0 + row) * 5 + mlane] = p0[r] + p1[r] + bpv;
            }
        }
    };

    __syncthreads();                                           // B1: arena visible

    // ---- level 1: 2-phase, ONE barrier ----
    // phase A: read ALL frags of rows 0-63; barrier; write rows 0-31.
    // phase B: read rows 64-127 (never written in L1); write rows 32-63
    // (their readers all drained at B2).
    {
        f16x8 af0[8], af1[8];
        read_frags(&AR[ 0 * HSTRIDE], af0);        // rows  0-31
        read_frags(&AR[32 * HSTRIDE], af1);        // rows 32-63
        __syncthreads();                                       // B2: reads of 0-63 done
        mfma_write(af0, &AR[ 0 * HSTRIDE]);        // write  0-15
        mfma_write(af1, &AR[16 * HSTRIDE]);        // write 16-31
        read_frags(&AR[64 * HSTRIDE], af0);        // rows 64-95  (untouched)
        read_frags(&AR[96 * HSTRIDE], af1);        // rows 96-127 (untouched)
        mfma_write(af0, &AR[32 * HSTRIDE]);        // write 32-47
        mfma_write(af1, &AR[48 * HSTRIDE]);        // write 48-63
    }
    __syncthreads();                                           // B3: L1 rows 0-63 final

    // ---- Seg A: L1 proj (all waves) + L2 (reads 0-63 -> 64-95) ----
    proj_to_outb(&AR[(16 * wave) * HSTRIDE], 16 * wave, 16);
    {
        f16x8 af[8];
        read_frags(&AR[0], af);
        mfma_write(af, &AR[64 * HSTRIDE]);
        read_frags(&AR[32 * HSTRIDE], af);
        mfma_write(af, &AR[80 * HSTRIDE]);
    }
    __syncthreads();                                           // B4

    // ---- Seg B: L2 proj + L3 (reads 64-95 -> 0-15) ----
    if (wave == 0) proj_to_outb(&AR[64 * HSTRIDE], 64, 16);
    if (wave == 1) proj_to_outb(&AR[80 * HSTRIDE], 80, 16);
    { f16x8 af[8]; read_frags(&AR[64 * HSTRIDE], af); mfma_write(af, &AR[0]); }
    __syncthreads();                                           // B5

    // ---- Seg C: L3 proj + L4 (reads 0-31 -> 32-47, valid 8) ----
    if (wave == 2) proj_to_outb(&AR[0], 96, 16);
    { f16x8 af[8]; read_frags(&AR[0], af); mfma_write(af, &AR[32 * HSTRIDE]); }
    __syncthreads();                                           // B6

    // ---- Seg D: L4 proj + L5 (reads 32-63 -> 0-15, valid 4) ----
    if (wave == 3) proj_to_outb(&AR[32 * HSTRIDE], 112, 8);
    { f16x8 af[8]; read_frags(&AR[32 * HSTRIDE], af); mfma_write(af, &AR[0]); }
    __syncthreads();                                           // B7

    // ---- Seg E: L5 proj + L6 (reads 0-31 -> 32-47, valid 2) ----
    if (wave == 0) proj_to_outb(&AR[0], 120, 4);
    { f16x8 af[8]; read_frags(&AR[0], af); mfma_write(af, &AR[32 * HSTRIDE]); }
    __syncthreads();                                           // B8

    // ---- Seg F: L6 proj + L7 (reads 32-63 -> 0-15, valid 1) ----
    if (wave == 1) proj_to_outb(&AR[32 * HSTRIDE], 124, 2);
    { f16x8 af[8]; read_frags(&AR[32 * HSTRIDE], af); mfma_write(af, &AR[0]); }
    __syncthreads();                                           // B9

    // ---- Seg G: L7 proj + Q store (AR row 0 = eighth-root) ----
    if (wave == 2) proj_to_outb(&AR[0], 126, 1);
    if (tid < 16)
        *(uint4*)&Q[(size_t)blockIdx.x * 128 + tid * 8] = *(const uint4*)&AR[tid * 8];
    __syncthreads();                                           // B10: outbox complete

    // ---- flush outbox: 127 rows x 5 floats, one global-store pass ----
    for (int t2 = tid; t2 < 635; t2 += 256) {
        const int lrow = t2 / 5;
        const int cls  = t2 - lrow * 5;
        int j, i;
        if      (lrow <  64) { j = 1; i = lrow;       }
        else if (lrow <  96) { j = 2; i = lrow - 64;  }
        else if (lrow < 112) { j = 3; i = lrow - 96;  }
        else if (lrow < 120) { j = 4; i = lrow - 112; }
        else if (lrow < 124) { j = 5; i = lrow - 120; }
        else if (lrow < 126) { j = 6; i = lrow - 124; }
        else                 { j = 7; i = 0;          }
        const size_t grow = (size_t)256 * (1024 - (2048 >> j))
                          + (size_t)tree * (1024 >> j) + (size_t)e * (128 >> j) + i;
        out[grow * 5 + cls] = OutB[t2];
    }
}

// ---------------- top 3 levels (8 eighth-roots -> 4 -> 2 -> 1), fp32 ----------------
__global__ __launch_bounds__(128, 4)
void rnn_top_kernel(const f16_t* __restrict__ Q,
                    const float* __restrict__ W,
                    const float* __restrict__ bW,
                    const float* __restrict__ P,
                    const float* __restrict__ bP,
                    float* __restrict__ out)
{
    __shared__ float qs[1024];
    __shared__ float hs[896];    // [0,512): level-8 nodes, [512,768): level-9, [768,896): root
    const int t    = threadIdx.x;
    const int tree = blockIdx.x;

    #pragma unroll
    for (int i = 0; i < 8; ++i)
        qs[t + i * 128] = (float)Q[(size_t)tree * 1024 + t + i * 128];
    __syncthreads();

    const float* wr = W + t * 256;

    // level 8: 4 nodes from 8 eighth-roots
    float s8[4];
    #pragma unroll
    for (int n = 0; n < 4; ++n) s8[n] = bW[t];
    for (int k = 0; k < 256; k += 4) {
        const float4 wv = *(const float4*)(wr + k);
        #pragma unroll
        for (int n = 0; n < 4; ++n) {
            const float* qb = qs + n * 256 + k;
            s8[n] += wv.x * qb[0] + wv.y * qb[1] + wv.z * qb[2] + wv.w * qb[3];
        }
    }
    #pragma unroll
    for (int n = 0; n < 4; ++n) hs[n * 128 + t] = fmaxf(s8[n], 0.f);
    __syncthreads();

    // level 9: 2 nodes
    float s9[2];
    s9[0] = s9[1] = bW[t];
    for (int k = 0; k < 256; k += 4) {
        const float4 wv = *(const float4*)(wr + k);
        #pragma unroll
        for (int m = 0; m < 2; ++m) {
            const float* hb = hs + m * 256 + k;
            s9[m] += wv.x * hb[0] + wv.y * hb[1] + wv.z * hb[2] + wv.w * hb[3];
        }
    }
    hs[512 + t] = fmaxf(s9[0], 0.f);
    hs[640 + t] = fmaxf(s9[1], 0.f);
    __syncthreads();

    // level 10: root
    float s10 = bW[t];
    for (int k = 0; k < 256; k += 4) {
        const float4 wv = *(const float4*)(wr + k);
        const float* hb = hs + 512 + k;
        s10 += wv.x * hb[0] + wv.y * hb[1] + wv.z * hb[2] + wv.w * hb[3];
    }
    hs[768 + t] = fmaxf(s10, 0.f);
    __syncthreads();

    // projections: 7 nodes x 5 classes
    if (t < 35) {
        const int node = t / 5, c = t % 5;
        float s = bP[c];
        const float* hb = hs + node * 128;
        for (int k = 0; k < 128; ++k) s += hb[k] * P[c * 128 + k];
        size_t row;
        if (node < 4)      row = 260096 + (size_t)tree * 4 + node;        // level 8 (n=4/tree)
        else if (node < 6) row = 261120 + (size_t)tree * 2 + (node - 4);  // level 9 (n=2/tree)
        else               row = 261632 + (size_t)tree;                   // level 10 root
        out[row * 5 + c] = s;
    }
}

extern "C" void kernel_launch(void* const* d_in, const int* in_sizes, int n_in,
                              void* d_out, int out_size, void* d_ws, size_t ws_size,
                              hipStream_t stream) {
    const float* leaves = (const float*)d_in[0];   // [256,1024,128] fp32
    const float* W      = (const float*)d_in[1];   // [128,256] fp32
    const float* bW     = (const float*)d_in[2];   // [128] fp32
    const float* P      = (const float*)d_in[3];   // [5,128] fp32
    const float* bP     = (const float*)d_in[4];   // [5] fp32
    float* out = (float*)d_out;                    // [256*1023, 5] fp32

    // ws layout (f16 elems): Wh 32768 | Ph 1024 | Q 262144  (~592 KB)
    f16_t* Wh = (f16_t*)d_ws;
    f16_t* Ph = Wh + 32768;
    f16_t* Q  = Wh + 32768 + 1024;

    prep_kernel<<<dim3(129), dim3(256), 0, stream>>>(W, P, Wh, Ph);
    forest_kernel<<<dim3(2048), dim3(256), 0, stream>>>(leaves, Wh, Ph, bW, bP, Q, out);
    rnn_top_kernel<<<dim3(256), dim3(128), 0, stream>>>(Q, W, bW, P, bP, out);
}

// Round 12
// 221.869 us; speedup vs baseline: 1.0665x; 1.0170x over previous
//
#include <hip/hip_runtime.h>
#include <hip/hip_bf16.h>
#include <hip/hip_fp16.h>

// RecursiveNN forest bottom-up pass, fp32 in / fp32 out.
// forest_kernel: one block per EIGHTH-tree (64 level-1 pair-rows).
// FINAL: exact round-7 structure — the measured optimum (220.5 us).
// Every neighboring variant measured worse: r8 bigger-segments +6 (LDS
// 54.7KB -> 2 blk/CU), r9 2-wave blocks +16 (VGPR 128/wave band), r10 G=4
// batching +8 (killed inter-block overlap), r11 fewer-barriers +5 (af live
// across barrier -> +32 VGPR -> 3 waves/SIMD). This kernel: in-place arena
// ping-pong, split-K MFMA chains, all projections via LDS outbox, zero
// global ops inside the barrier path, 13 cheap lgkm-only barriers.
// prep converts W/P to f16 once. rnn_top: top 3 levels fp32 (verified).

typedef _Float16 f16_t;
typedef _Float16 f16x4 __attribute__((ext_vector_type(4)));
typedef _Float16 f16x8 __attribute__((ext_vector_type(8)));
typedef float f32x4 __attribute__((ext_vector_type(4)));

#define HSTRIDE 136   // f16 elems per row slot: 272 B, 16B-aligned

static __device__ __forceinline__ f32x4 mfma16(f16x8 a, f16x8 b, f32x4 c) {
    return __builtin_amdgcn_mfma_f32_16x16x32_f16(a, b, c, 0, 0, 0);
}

// One-shot: W [128,256] fp32 -> fp16 Wh; P [5,128] fp32 -> fp16 Ph.
__global__ void prep_kernel(const float* __restrict__ W, const float* __restrict__ P,
                            f16_t* __restrict__ Wh, f16_t* __restrict__ Ph) {
    if (blockIdx.x < 128) {
        const int i = blockIdx.x * 256 + threadIdx.x;
        Wh[i] = (f16_t)W[i];
    } else {
        for (int i = threadIdx.x; i < 640; i += 256) Ph[i] = (f16_t)P[i];
    }
}

// ---------------- fused levels 1..7 for one 64-pair-row eighth-tree ----------------
__global__ __launch_bounds__(256, 2)
void forest_kernel(const float* __restrict__ leaves,
                   const f16_t* __restrict__ Wh,
                   const f16_t* __restrict__ Ph,
                   const float* __restrict__ bW,
                   const float* __restrict__ bP,
                   f16_t* __restrict__ Q,          // [2048,128] eighth-roots
                   float* __restrict__ out)
{
    __shared__ f16_t AR[128 * HSTRIDE];          // 34816 B: leaf arena + ping-pong H
    __shared__ float OutB[640];                  // 2560 B: proj outbox, 127 rows x 5

    const int tid   = threadIdx.x;
    const int wave  = tid >> 6;
    const int lane  = tid & 63;
    const int mlane = lane & 15;
    const int q     = lane >> 4;
    const int tree  = blockIdx.x >> 3;
    const int e     = blockIdx.x & 7;
    const float* leafbase = leaves + (size_t)blockIdx.x * 16384;

    // W b-frags (gemm_bt, verified): lane holds W[col][k*32 + q*8 + e]
    f16x8 wh[2][8];
    float bwv[2];
    #pragma unroll
    for (int n = 0; n < 2; ++n) {
        const int col = wave * 32 + n * 16 + mlane;
        bwv[n] = bW[col];
        #pragma unroll
        for (int k = 0; k < 8; ++k)
            wh[n][k] = *(const f16x8*)&Wh[col * 256 + k * 32 + q * 8];
    }

    // P b-frags, N padded 5->16 (zero rows for mlane>=5)
    f16x8 pb[4] = {};
    if (mlane < 5) {
        #pragma unroll
        for (int kb = 0; kb < 4; ++kb)
            pb[kb] = *(const f16x8*)&Ph[mlane * 128 + kb * 32 + q * 8];
    }
    const float bpv = (mlane < 5) ? bP[mlane] : 0.f;

    // ---- whole-block leaf preload: 64 KB fp32 -> f16 arena, 16 loads in flight ----
    {
        float4 t[16];
        #pragma unroll
        for (int r = 0; r < 16; ++r)
            t[r] = ((const float4*)leafbase)[tid + r * 256];
        #pragma unroll
        for (int r = 0; r < 16; ++r) {
            const int idx = tid + r * 256;             // 4096 float4 = 128 leaf rows
            const int row = idx >> 5;
            const int c4  = idx & 31;
            f16x4 t4 = { (f16_t)t[r].x, (f16_t)t[r].y, (f16_t)t[r].z, (f16_t)t[r].w };
            *(f16x4*)&AR[row * HSTRIDE + c4 * 4] = t4;
        }
    }

    // read A-frags for a 32-row window at src (verified fragment pattern)
    auto read_frags = [&](const f16_t* src, f16x8* af) {
        #pragma unroll
        for (int k = 0; k < 8; ++k) {
            const int off  = k * 64 + q * 16;    // byte offset in 512B pair-row
            const int trow = off >> 8;
            const int ce   = (off & 255) >> 1;
            af[k] = *(const f16x8*)&src[(2 * mlane + trow) * HSTRIDE + ce];
        }
    };
    // MFMA (split-K: 4 independent chains of 4) + bias + relu -> 16-row frame
    auto mfma_write = [&](const f16x8* af, f16_t* dst) {
        f32x4 a0 = {}, b0 = {}, a1 = {}, b1 = {};
        #pragma unroll
        for (int k = 0; k < 4; ++k) {
            a0 = mfma16(af[k], wh[0][k], a0);
            a1 = mfma16(af[k], wh[1][k], a1);
        }
        #pragma unroll
        for (int k = 4; k < 8; ++k) {
            b0 = mfma16(af[k], wh[0][k], b0);
            b1 = mfma16(af[k], wh[1][k], b1);
        }
        #pragma unroll
        for (int r = 0; r < 4; ++r) {
            float v0 = fmaxf(a0[r] + b0[r] + bwv[0], 0.f);
            float v1 = fmaxf(a1[r] + b1[r] + bwv[1], 0.f);
            dst[(q * 4 + r) * HSTRIDE + wave * 32 + mlane]      = (f16_t)v0;
            dst[(q * 4 + r) * HSTRIDE + wave * 32 + 16 + mlane] = (f16_t)v1;
        }
    };
    // proj of 16 H rows at hb -> OutB rows [orow0, orow0+valid); 2x2 chains
    auto proj_to_outb = [&](const f16_t* hb, int orow0, int valid) {
        f32x4 p0 = {}, p1 = {};
        {
            const f16x8 h0 = *(const f16x8*)&hb[mlane * HSTRIDE + 0 * 32 + q * 8];
            const f16x8 h1 = *(const f16x8*)&hb[mlane * HSTRIDE + 1 * 32 + q * 8];
            const f16x8 h2 = *(const f16x8*)&hb[mlane * HSTRIDE + 2 * 32 + q * 8];
            const f16x8 h3 = *(const f16x8*)&hb[mlane * HSTRIDE + 3 * 32 + q * 8];
            p0 = mfma16(h0, pb[0], p0); p1 = mfma16(h1, pb[1], p1);
            p0 = mfma16(h2, pb[2], p0); p1 = mfma16(h3, pb[3], p1);
        }
        if (mlane < 5) {
            #pragma unroll
            for (int r = 0; r < 4; ++r) {
                const int row = q * 4 + r;       // D layout: row=q*4+r, col=mlane (verified)
                if (row < valid) OutB[(orow0 + row) * 5 + mlane] = p0[r] + p1[r] + bpv;
            }
        }
    };

    __syncthreads();                                           // B1: arena visible

    // ---- level 1: 4 in-arena ping-pong steps ----
    // step c: read rows [32c,32c+32) ; barrier ; write [16c,16c+16)
    #pragma unroll
    for (int c = 0; c < 4; ++c) {
        f16x8 af[8];
        read_frags(&AR[(32 * c) * HSTRIDE], af);
        __syncthreads();                                       // B2..B5
        mfma_write(af, &AR[(16 * c) * HSTRIDE]);
    }
    __syncthreads();                                           // B6: L1 rows 0-63 final

    // ---- Seg A: L1 proj (all waves) + L2 (reads 0-63 -> 64-95) ----
    proj_to_outb(&AR[(16 * wave) * HSTRIDE], 16 * wave, 16);
    {
        f16x8 af[8];
        read_frags(&AR[0], af);
        mfma_write(af, &AR[64 * HSTRIDE]);
        read_frags(&AR[32 * HSTRIDE], af);
        mfma_write(af, &AR[80 * HSTRIDE]);
    }
    __syncthreads();                                           // B7

    // ---- Seg B: L2 proj + L3 (reads 64-95 -> 0-15) ----
    if (wave == 0) proj_to_outb(&AR[64 * HSTRIDE], 64, 16);
    if (wave == 1) proj_to_outb(&AR[80 * HSTRIDE], 80, 16);
    { f16x8 af[8]; read_frags(&AR[64 * HSTRIDE], af); mfma_write(af, &AR[0]); }
    __syncthreads();                                           // B8

    // ---- Seg C: L3 proj + L4 (reads 0-31 -> 32-47, valid 8) ----
    if (wave == 2) proj_to_outb(&AR[0], 96, 16);
    { f16x8 af[8]; read_frags(&AR[0], af); mfma_write(af, &AR[32 * HSTRIDE]); }
    __syncthreads();                                           // B9

    // ---- Seg D: L4 proj + L5 (reads 32-63 -> 0-15, valid 4) ----
    if (wave == 3) proj_to_outb(&AR[32 * HSTRIDE], 112, 8);
    { f16x8 af[8]; read_frags(&AR[32 * HSTRIDE], af); mfma_write(af, &AR[0]); }
    __syncthreads();                                           // B10

    // ---- Seg E: L5 proj + L6 (reads 0-31 -> 32-47, valid 2) ----
    if (wave == 0) proj_to_outb(&AR[0], 120, 4);
    { f16x8 af[8]; read_frags(&AR[0], af); mfma_write(af, &AR[32 * HSTRIDE]); }
    __syncthreads();                                           // B11

    // ---- Seg F: L6 proj + L7 (reads 32-63 -> 0-15, valid 1) ----
    if (wave == 1) proj_to_outb(&AR[32 * HSTRIDE], 124, 2);
    { f16x8 af[8]; read_frags(&AR[32 * HSTRIDE], af); mfma_write(af, &AR[0]); }
    __syncthreads();                                           // B12

    // ---- Seg G: L7 proj + Q store (AR row 0 = eighth-root) ----
    if (wave == 2) proj_to_outb(&AR[0], 126, 1);
    if (tid < 16)
        *(uint4*)&Q[(size_t)blockIdx.x * 128 + tid * 8] = *(const uint4*)&AR[tid * 8];
    __syncthreads();                                           // B13: outbox complete

    // ---- flush outbox: 127 rows x 5 floats, one global-store pass ----
    for (int t2 = tid; t2 < 635; t2 += 256) {
        const int lrow = t2 / 5;
        const int cls  = t2 - lrow * 5;
        int j, i;
        if      (lrow <  64) { j = 1; i = lrow;       }
        else if (lrow <  96) { j = 2; i = lrow - 64;  }
        else if (lrow < 112) { j = 3; i = lrow - 96;  }
        else if (lrow < 120) { j = 4; i = lrow - 112; }
        else if (lrow < 124) { j = 5; i = lrow - 120; }
        else if (lrow < 126) { j = 6; i = lrow - 124; }
        else                 { j = 7; i = 0;          }
        const size_t grow = (size_t)256 * (1024 - (2048 >> j))
                          + (size_t)tree * (1024 >> j) + (size_t)e * (128 >> j) + i;
        out[grow * 5 + cls] = OutB[t2];
    }
}

// ---------------- top 3 levels (8 eighth-roots -> 4 -> 2 -> 1), fp32 ----------------
__global__ __launch_bounds__(128, 4)
void rnn_top_kernel(const f16_t* __restrict__ Q,
                    const float* __restrict__ W,
                    const float* __restrict__ bW,
                    const float* __restrict__ P,
                    const float* __restrict__ bP,
                    float* __restrict__ out)
{
    __shared__ float qs[1024];
    __shared__ float hs[896];    // [0,512): level-8 nodes, [512,768): level-9, [768,896): root
    const int t    = threadIdx.x;
    const int tree = blockIdx.x;

    #pragma unroll
    for (int i = 0; i < 8; ++i)
        qs[t + i * 128] = (float)Q[(size_t)tree * 1024 + t + i * 128];
    __syncthreads();

    const float* wr = W + t * 256;

    // level 8: 4 nodes from 8 eighth-roots
    float s8[4];
    #pragma unroll
    for (int n = 0; n < 4; ++n) s8[n] = bW[t];
    for (int k = 0; k < 256; k += 4) {
        const float4 wv = *(const float4*)(wr + k);
        #pragma unroll
        for (int n = 0; n < 4; ++n) {
            const float* qb = qs + n * 256 + k;
            s8[n] += wv.x * qb[0] + wv.y * qb[1] + wv.z * qb[2] + wv.w * qb[3];
        }
    }
    #pragma unroll
    for (int n = 0; n < 4; ++n) hs[n * 128 + t] = fmaxf(s8[n], 0.f);
    __syncthreads();

    // level 9: 2 nodes
    float s9[2];
    s9[0] = s9[1] = bW[t];
    for (int k = 0; k < 256; k += 4) {
        const float4 wv = *(const float4*)(wr + k);
        #pragma unroll
        for (int m = 0; m < 2; ++m) {
            const float* hb = hs + m * 256 + k;
            s9[m] += wv.x * hb[0] + wv.y * hb[1] + wv.z * hb[2] + wv.w * hb[3];
        }
    }
    hs[512 + t] = fmaxf(s9[0], 0.f);
    hs[640 + t] = fmaxf(s9[1], 0.f);
    __syncthreads();

    // level 10: root
    float s10 = bW[t];
    for (int k = 0; k < 256; k += 4) {
        const float4 wv = *(const float4*)(wr + k);
        const float* hb = hs + 512 + k;
        s10 += wv.x * hb[0] + wv.y * hb[1] + wv.z * hb[2] + wv.w * hb[3];
    }
    hs[768 + t] = fmaxf(s10, 0.f);
    __syncthreads();

    // projections: 7 nodes x 5 classes
    if (t < 35) {
        const int node = t / 5, c = t % 5;
        float s = bP[c];
        const float* hb = hs + node * 128;
        for (int k = 0; k < 128; ++k) s += hb[k] * P[c * 128 + k];
        size_t row;
        if (node < 4)      row = 260096 + (size_t)tree * 4 + node;        // level 8 (n=4/tree)
        else if (node < 6) row = 261120 + (size_t)tree * 2 + (node - 4);  // level 9 (n=2/tree)
        else               row = 261632 + (size_t)tree;                   // level 10 root
        out[row * 5 + c] = s;
    }
}

extern "C" void kernel_launch(void* const* d_in, const int* in_sizes, int n_in,
                              void* d_out, int out_size, void* d_ws, size_t ws_size,
                              hipStream_t stream) {
    const float* leaves = (const float*)d_in[0];   // [256,1024,128] fp32
    const float* W      = (const float*)d_in[1];   // [128,256] fp32
    const float* bW     = (const float*)d_in[2];   // [128] fp32
    const float* P      = (const float*)d_in[3];   // [5,128] fp32
    const float* bP     = (const float*)d_in[4];   // [5] fp32
    float* out = (float*)d_out;                    // [256*1023, 5] fp32

    // ws layout (f16 elems): Wh 32768 | Ph 1024 | Q 262144  (~592 KB)
    f16_t* Wh = (f16_t*)d_ws;
    f16_t* Ph = Wh + 32768;
    f16_t* Q  = Wh + 32768 + 1024;

    prep_kernel<<<dim3(129), dim3(256), 0, stream>>>(W, P, Wh, Ph);
    forest_kernel<<<dim3(2048), dim3(256), 0, stream>>>(leaves, Wh, Ph, bW, bP, Q, out);
    rnn_top_kernel<<<dim3(256), dim3(128), 0, stream>>>(Q, W, bW, P, bP, out);
}